// Round 2
// baseline (732.189 us; speedup 1.0000x reference)
//
#include <hip/hip_runtime.h>
#include <hip/hip_bf16.h>

#define G_ 8
#define SCALE_ 0.125f
#define EPS_ 1e-5f
#define BATCH 64
#define CCH 512
#define DD 1024

typedef __attribute__((ext_vector_type(8))) short short8;
typedef __attribute__((ext_vector_type(4))) short short4v;
typedef __attribute__((ext_vector_type(4))) float float4v;

__device__ __forceinline__ unsigned short bf16_rne(float f) {
    union { float f; unsigned u; } x; x.f = f;
    unsigned u = x.u;
    unsigned r = (u + 0x7fffu + ((u >> 16) & 1u)) >> 16;
    return (unsigned short)r;
}
__device__ __forceinline__ float bf16_to_f(unsigned short h) {
    union { unsigned u; float f; } x; x.u = ((unsigned)h) << 16;
    return x.f;
}

// ---------------- zero att + ysum + ysum2 (contiguous 1536 floats) ----------------
__global__ void zero_att_kernel(float* att) {
    int t = threadIdx.x;
    if (t < 512) {
        att[t]         = 0.0f;
        att[t + 512]   = 0.0f;  // ysum
        att[t + 1024]  = 0.0f;  // ysum2
    }
}

// ---------------- W2[g*64+o, c] = sum_cg Wz[g,o,cg] * Wt[g*64+cg, c] (bf16 out) ----------------
__global__ __launch_bounds__(256) void w2_kernel(const float* __restrict__ Wt,
                                                 const float* __restrict__ Wz,
                                                 unsigned short* __restrict__ W2bf) {
    int idx = blockIdx.x * 256 + threadIdx.x;     // 0..262143
    int c  = idx & 511;
    int og = idx >> 9;                             // 0..511
    int g  = og >> 6;
    int o  = og & 63;
    const float* wz = Wz + (g * 64 + o) * 64;      // Wz[g][o][*]
    const float* wt = Wt + (size_t)(g * 64) * 512 + c;
    float acc = 0.0f;
#pragma unroll 8
    for (int cg = 0; cg < 64; ++cg) acc += wz[cg] * wt[(size_t)cg * 512];
    W2bf[idx] = bf16_rne(acc);
}

// ---------------- M2[(i*512+j)*8 + g] = sum_o Wp[g*64+o, i] * Wg[g*64+o, j] (fp32) ----------------
__global__ __launch_bounds__(256) void m2_kernel(const float* __restrict__ Wp,
                                                 const float* __restrict__ Wg,
                                                 float* __restrict__ M2) {
    __shared__ __align__(16) float Ap[64][64];
    __shared__ __align__(16) float Bg[64][64];
    int g  = blockIdx.x & 7;
    int tj = (blockIdx.x >> 3) & 7;
    int ti = blockIdx.x >> 6;
    int i0 = ti * 64, j0 = tj * 64;
    int tid = threadIdx.x;
    int tx = tid & 15, ty = tid >> 4;
#pragma unroll
    for (int r = 0; r < 16; ++r) {
        int f = tid + r * 256;
        int o = f >> 6, col = f & 63;
        Ap[o][col] = Wp[(size_t)(g * 64 + o) * 512 + i0 + col];
        Bg[o][col] = Wg[(size_t)(g * 64 + o) * 512 + j0 + col];
    }
    __syncthreads();
    float acc[4][4] = {};
#pragma unroll 4
    for (int o = 0; o < 64; ++o) {
        float4v av = *(const float4v*)&Ap[o][ty * 4];
        float4v bv = *(const float4v*)&Bg[o][tx * 4];
#pragma unroll
        for (int a = 0; a < 4; ++a)
#pragma unroll
            for (int b = 0; b < 4; ++b) acc[a][b] += av[a] * bv[b];
    }
#pragma unroll
    for (int a = 0; a < 4; ++a)
#pragma unroll
        for (int b = 0; b < 4; ++b)
            M2[((size_t)(i0 + ty * 4 + a) * 512 + (j0 + tx * 4 + b)) * 8 + g] = acc[a][b];
}

// ---------------- S-GEMM (split-bf16, 3 passes) with fused att reduction ----------------
// S[b,i,j] = sum_d q[b,i,d]*k[b,j,d];  att_raw[b,g] += sum_{i,j in tile} M2[i,j,g]*S[b,i,j]
#define LDK 40  // padded K stride in shorts (32 + 8)

__global__ __launch_bounds__(256) void sgemm_att_kernel(const float* __restrict__ q,
                                                        const float* __restrict__ kmat,
                                                        const float* __restrict__ M2,
                                                        float* __restrict__ att) {
    __shared__ __align__(16) short Ah[128 * LDK];
    __shared__ __align__(16) short Al[128 * LDK];
    __shared__ __align__(16) short Bh[128 * LDK];
    __shared__ __align__(16) short Bl[128 * LDK];
    __shared__ float red[256 * 8];

    int b  = blockIdx.y;
    int i0 = (blockIdx.x & 3) * 128;
    int j0 = (blockIdx.x >> 2) * 128;
    const float* qb = q    + (size_t)b * CCH * DD;
    const float* kb = kmat + (size_t)b * CCH * DD;

    int tid  = threadIdx.x;
    int wave = tid >> 6, lane = tid & 63;
    int quad = lane >> 4, l15 = lane & 15;
    int wm = (wave >> 1) * 64, wn = (wave & 1) * 64;

    float4v acc[4][4];
#pragma unroll
    for (int a = 0; a < 4; ++a)
#pragma unroll
        for (int c = 0; c < 4; ++c) acc[a][c] = (float4v){0.f, 0.f, 0.f, 0.f};

    for (int kt = 0; kt < DD; kt += 32) {
        // stage A (q rows) and B (k rows), fp32 -> bf16 hi/lo
#pragma unroll
        for (int r = 0; r < 4; ++r) {
            int f   = tid + r * 256;
            int row = f >> 3;
            int c4  = (f & 7) * 4;
            float4v qa = *(const float4v*)(qb + (size_t)(i0 + row) * DD + kt + c4);
            float4v ka = *(const float4v*)(kb + (size_t)(j0 + row) * DD + kt + c4);
            short4v qh, ql, kh, kl;
#pragma unroll
            for (int e = 0; e < 4; ++e) {
                float x = qa[e];
                unsigned short h = bf16_rne(x);
                qh[e] = (short)h;
                ql[e] = (short)bf16_rne(x - bf16_to_f(h));
                float y = ka[e];
                unsigned short h2 = bf16_rne(y);
                kh[e] = (short)h2;
                kl[e] = (short)bf16_rne(y - bf16_to_f(h2));
            }
            *(short4v*)&Ah[row * LDK + c4] = qh;
            *(short4v*)&Al[row * LDK + c4] = ql;
            *(short4v*)&Bh[row * LDK + c4] = kh;
            *(short4v*)&Bl[row * LDK + c4] = kl;
        }
        __syncthreads();

        short8 ah[4], al[4], bh8[4], bl8[4];
#pragma unroll
        for (int mi = 0; mi < 4; ++mi) {
            int rr = wm + mi * 16 + l15;
            ah[mi] = *(const short8*)&Ah[rr * LDK + quad * 8];
            al[mi] = *(const short8*)&Al[rr * LDK + quad * 8];
        }
#pragma unroll
        for (int ni = 0; ni < 4; ++ni) {
            int rr = wn + ni * 16 + l15;
            bh8[ni] = *(const short8*)&Bh[rr * LDK + quad * 8];
            bl8[ni] = *(const short8*)&Bl[rr * LDK + quad * 8];
        }
#pragma unroll
        for (int mi = 0; mi < 4; ++mi)
#pragma unroll
            for (int ni = 0; ni < 4; ++ni) {
                acc[mi][ni] = __builtin_amdgcn_mfma_f32_16x16x32_bf16(ah[mi], bh8[ni], acc[mi][ni], 0, 0, 0);
                acc[mi][ni] = __builtin_amdgcn_mfma_f32_16x16x32_bf16(al[mi], bh8[ni], acc[mi][ni], 0, 0, 0);
                acc[mi][ni] = __builtin_amdgcn_mfma_f32_16x16x32_bf16(ah[mi], bl8[ni], acc[mi][ni], 0, 0, 0);
            }
        __syncthreads();
    }

    // epilogue: att partials via M2 (layout [i][j][g], g contiguous)
    float r8[8] = {};
#pragma unroll
    for (int mi = 0; mi < 4; ++mi)
#pragma unroll
        for (int ni = 0; ni < 4; ++ni)
#pragma unroll
            for (int r = 0; r < 4; ++r) {
                int i = i0 + wm + mi * 16 + quad * 4 + r;
                int j = j0 + wn + ni * 16 + l15;
                float s = acc[mi][ni][r];
                const float* mp = M2 + ((size_t)i * 512 + j) * 8;
                float4v m0 = *(const float4v*)mp;
                float4v m1 = *(const float4v*)(mp + 4);
                r8[0] += s * m0[0]; r8[1] += s * m0[1]; r8[2] += s * m0[2]; r8[3] += s * m0[3];
                r8[4] += s * m1[0]; r8[5] += s * m1[1]; r8[6] += s * m1[2]; r8[7] += s * m1[3];
            }
#pragma unroll
    for (int g8 = 0; g8 < 8; ++g8) red[tid * 8 + g8] = r8[g8];
    __syncthreads();
    for (int off = 128; off > 0; off >>= 1) {
        if (tid < off) {
#pragma unroll
            for (int g8 = 0; g8 < 8; ++g8) red[tid * 8 + g8] += red[(tid + off) * 8 + g8];
        }
        __syncthreads();
    }
    if (tid < 8) atomicAdd(&att[b * 8 + tid], red[tid]);
}

// ---------------- y-GEMM: y[b,o,d] = sum_c W2[o,c] * v[b,c,d]  (fp32 out into d_out)
// 512 threads / 8 waves; block = 256 o x 128 d => v read only 2x (was 4x).
// (Full-o per block would reach 1x but needs 176+ VGPR / 8 waves/CU — worse trade.)
// Fused per-wave GroupNorm partial stats (each wave's 64 o-rows = one (b,g) group).
__global__ __launch_bounds__(512, 4) void ygemm_kernel(const unsigned short* __restrict__ W2bf,
                                                       const float* __restrict__ v,
                                                       float* __restrict__ y,
                                                       float* __restrict__ ysum,
                                                       float* __restrict__ ysum2) {
    __shared__ __align__(16) short As[256 * LDK];  // W2 tile: 256 o x 32 c
    __shared__ __align__(16) short Bs[128 * LDK];  // v tile (transposed): 128 d x 32 c

    int b  = blockIdx.y;
    int o0 = (blockIdx.x & 1) * 256;
    int d0 = (blockIdx.x >> 1) * 128;
    const float* vb = v + (size_t)b * CCH * DD;

    int tid  = threadIdx.x;
    int wave = tid >> 6, lane = tid & 63;
    int quad = lane >> 4, l15 = lane & 15;
    int wo = wave >> 1, wd = wave & 1;          // wave tile: 64 o x 64 d

    float4v acc[4][4];
#pragma unroll
    for (int a = 0; a < 4; ++a)
#pragma unroll
        for (int c = 0; c < 4; ++c) acc[a][c] = (float4v){0.f, 0.f, 0.f, 0.f};

    int nB = tid & 127;        // d-index within tile for B staging
    int kB = (tid >> 7) * 8;   // k octet base (0..24)

    for (int kt = 0; kt < CCH; kt += 32) {
        // A: W2 rows (already bf16, k-contiguous): 256x32 shorts = 1024 short8 / 512 thr
#pragma unroll
        for (int r = 0; r < 2; ++r) {
            int f   = tid + r * 512;
            int row = f >> 2;
            int c8  = (f & 3) * 8;
            short8 w = *(const short8*)(W2bf + (size_t)(o0 + row) * 512 + kt + c8);
            *(short8*)&As[row * LDK + c8] = w;
        }
        // B: transpose-gather v[c,d] -> Bs[d][c]: 128x32 = 512 short8 / 512 thr
        {
            short8 bsv;
#pragma unroll
            for (int jj = 0; jj < 8; ++jj) {
                float f = vb[(size_t)(kt + kB + jj) * DD + d0 + nB];
                bsv[jj] = (short)bf16_rne(f);
            }
            *(short8*)&Bs[nB * LDK + kB] = bsv;
        }
        __syncthreads();

        short8 af[4], bf[4];
#pragma unroll
        for (int mi = 0; mi < 4; ++mi)
            af[mi] = *(const short8*)&As[(wo * 64 + mi * 16 + l15) * LDK + quad * 8];
#pragma unroll
        for (int ni = 0; ni < 4; ++ni)
            bf[ni] = *(const short8*)&Bs[(wd * 64 + ni * 16 + l15) * LDK + quad * 8];
#pragma unroll
        for (int mi = 0; mi < 4; ++mi)
#pragma unroll
            for (int ni = 0; ni < 4; ++ni)
                acc[mi][ni] = __builtin_amdgcn_mfma_f32_16x16x32_bf16(af[mi], bf[ni], acc[mi][ni], 0, 0, 0);
        __syncthreads();
    }

    float* yb = y + (size_t)b * CCH * DD;
    float s = 0.f, s2 = 0.f;
#pragma unroll
    for (int mi = 0; mi < 4; ++mi)
#pragma unroll
        for (int ni = 0; ni < 4; ++ni) {
            int o = o0 + wo * 64 + mi * 16 + quad * 4;
            int d = d0 + wd * 64 + ni * 16 + l15;
#pragma unroll
            for (int r = 0; r < 4; ++r) {
                float val = acc[mi][ni][r];
                yb[(size_t)(o + r) * DD + d] = val;
                s  += val;
                s2 += val * val;
            }
        }
    // wave-level reduce: all 64 o-rows of this wave are one (b,g) group
#pragma unroll
    for (int off = 32; off > 0; off >>= 1) {
        s  += __shfl_down(s, off, 64);
        s2 += __shfl_down(s2, off, 64);
    }
    if (lane == 0) {
        int g = (o0 >> 6) + wo;
        atomicAdd(&ysum[b * 8 + g], s);
        atomicAdd(&ysum2[b * 8 + g], s2);
    }
}

// ---------------- finalize: scl = a/sqrt(a^2*var+eps), mean  (from fused sums) ----------------
__global__ void finalize_kernel(const float* __restrict__ att,
                                const float* __restrict__ ysum,
                                const float* __restrict__ ysum2,
                                float* __restrict__ scl,
                                float* __restrict__ meanp) {
    int bg = threadIdx.x;
    if (bg < 512) {
        float inv = 1.0f / 65536.0f;
        float m = ysum[bg] * inv;
        float var = ysum2[bg] * inv - m * m;
        float a = att[bg] * SCALE_;
        scl[bg] = a / sqrtf(a * a * var + EPS_);
        meanp[bg] = m;
    }
}

// ---------------- final: out = gamma[c]*scl*(y-mean) + beta[c] + v  (in-place on d_out) ----------------
__global__ __launch_bounds__(256) void final_kernel(const float* __restrict__ v,
                                                    const float* __restrict__ gamma,
                                                    const float* __restrict__ beta,
                                                    const float* __restrict__ scl,
                                                    const float* __restrict__ meanp,
                                                    float* __restrict__ out) {
    size_t idx = ((size_t)blockIdx.x * 256 + threadIdx.x) * 4;
    int c  = (int)((idx >> 10) & 511);
    int bg = (int)(idx >> 19) * 8 + (c >> 6);
    float4v y4 = *(const float4v*)(out + idx);
    float4v v4 = *(const float4v*)(v + idx);
    float sc = scl[bg] * gamma[c];
    float sh = beta[c] - sc * meanp[bg];
    float4v o4;
    o4[0] = y4[0] * sc + sh + v4[0];
    o4[1] = y4[1] * sc + sh + v4[1];
    o4[2] = y4[2] * sc + sh + v4[2];
    o4[3] = y4[3] * sc + sh + v4[3];
    *(float4v*)(out + idx) = o4;
}

extern "C" void kernel_launch(void* const* d_in, const int* in_sizes, int n_in,
                              void* d_out, int out_size, void* d_ws, size_t ws_size,
                              hipStream_t stream) {
    const float* q     = (const float*)d_in[0];
    const float* kmat  = (const float*)d_in[1];
    const float* v     = (const float*)d_in[2];
    const float* Wt    = (const float*)d_in[3];
    const float* Wp    = (const float*)d_in[4];
    const float* Wg    = (const float*)d_in[5];
    const float* Wz    = (const float*)d_in[6];
    const float* gamma = (const float*)d_in[7];
    const float* beta  = (const float*)d_in[8];
    float* out = (float*)d_out;

    char* ws = (char*)d_ws;
    float*          M2    = (float*)ws;                       // 8 MB  (512*512*8 fp32)
    unsigned short* W2bf  = (unsigned short*)(ws + 8388608);  // 512 KB
    float*          att   = (float*)(ws + 8912896);           // 2 KB
    float*          ysum  = (float*)(ws + 8914944);           // 2 KB
    float*          ysum2 = (float*)(ws + 8916992);           // 2 KB
    float*          scl   = (float*)(ws + 8919040);           // 2 KB
    float*          meanp = (float*)(ws + 8921088);           // 2 KB

    hipLaunchKernelGGL(zero_att_kernel, dim3(1), dim3(512), 0, stream, att);
    hipLaunchKernelGGL(w2_kernel, dim3(1024), dim3(256), 0, stream, Wt, Wz, W2bf);
    hipLaunchKernelGGL(m2_kernel, dim3(512), dim3(256), 0, stream, Wp, Wg, M2);
    hipLaunchKernelGGL(sgemm_att_kernel, dim3(16, 64), dim3(256), 0, stream, q, kmat, M2, att);
    hipLaunchKernelGGL(ygemm_kernel, dim3(16, 64), dim3(512), 0, stream, W2bf, v, out, ysum, ysum2);
    hipLaunchKernelGGL(finalize_kernel, dim3(1), dim3(512), 0, stream, att, ysum, ysum2, scl, meanp);
    hipLaunchKernelGGL(final_kernel, dim3(32768), dim3(256), 0, stream, v, gamma, beta, scl, meanp, out);
}

// Round 3
// 644.913 us; speedup vs baseline: 1.1353x; 1.1353x over previous
//
#include <hip/hip_runtime.h>
#include <hip/hip_bf16.h>

#define G_ 8
#define SCALE_ 0.125f
#define EPS_ 1e-5f
#define BATCH 64
#define CCH 512
#define DD 1024

typedef __attribute__((ext_vector_type(8))) short short8;
typedef __attribute__((ext_vector_type(4))) short short4v;
typedef __attribute__((ext_vector_type(4))) float float4v;

__device__ __forceinline__ unsigned short bf16_rne(float f) {
    union { float f; unsigned u; } x; x.f = f;
    unsigned u = x.u;
    unsigned r = (u + 0x7fffu + ((u >> 16) & 1u)) >> 16;
    return (unsigned short)r;
}
__device__ __forceinline__ short f2bf(float f) {
    __hip_bfloat16 h = __float2bfloat16(f);
    return *reinterpret_cast<short*>(&h);
}

// LDS swizzle for [rows][32-short] tiles: XOR short-index bits 3-5 with (row>>1)&7.
// Involution within each 128B (2-row) line pair; preserves 8B/16B alignment.
#define SWZI(row, so) ((((row) * 32) + (so)) ^ (((row) & 14) << 2))

// ---------------- zero att + ysum + ysum2 (contiguous 1536 floats) ----------------
__global__ void zero_att_kernel(float* att) {
    int t = threadIdx.x;
    if (t < 512) {
        att[t]        = 0.0f;
        att[t + 512]  = 0.0f;  // ysum
        att[t + 1024] = 0.0f;  // ysum2
    }
}

// ---------------- W2[g*64+o, c] = sum_cg Wz[g,o,cg] * Wt[g*64+cg, c] (bf16 out) ----------------
__global__ __launch_bounds__(256) void w2_kernel(const float* __restrict__ Wt,
                                                 const float* __restrict__ Wz,
                                                 unsigned short* __restrict__ W2bf) {
    int idx = blockIdx.x * 256 + threadIdx.x;     // 0..262143
    int c  = idx & 511;
    int og = idx >> 9;                             // 0..511
    int g  = og >> 6;
    int o  = og & 63;
    const float* wz = Wz + (g * 64 + o) * 64;      // Wz[g][o][*]
    const float* wt = Wt + (size_t)(g * 64) * 512 + c;
    float acc = 0.0f;
#pragma unroll 8
    for (int cg = 0; cg < 64; ++cg) acc += wz[cg] * wt[(size_t)cg * 512];
    W2bf[idx] = (unsigned short)f2bf(acc);
}

// ---------------- M2[(i*512+j)*8 + g] = sum_o Wp[g*64+o, i] * Wg[g*64+o, j] (fp32) ----------------
__global__ __launch_bounds__(256) void m2_kernel(const float* __restrict__ Wp,
                                                 const float* __restrict__ Wg,
                                                 float* __restrict__ M2) {
    __shared__ __align__(16) float Ap[64][64];
    __shared__ __align__(16) float Bg[64][64];
    int g  = blockIdx.x & 7;
    int tj = (blockIdx.x >> 3) & 7;
    int ti = blockIdx.x >> 6;
    int i0 = ti * 64, j0 = tj * 64;
    int tid = threadIdx.x;
    int tx = tid & 15, ty = tid >> 4;
#pragma unroll
    for (int r = 0; r < 16; ++r) {
        int f = tid + r * 256;
        int o = f >> 6, col = f & 63;
        Ap[o][col] = Wp[(size_t)(g * 64 + o) * 512 + i0 + col];
        Bg[o][col] = Wg[(size_t)(g * 64 + o) * 512 + j0 + col];
    }
    __syncthreads();
    float acc[4][4] = {};
#pragma unroll 4
    for (int o = 0; o < 64; ++o) {
        float4v av = *(const float4v*)&Ap[o][ty * 4];
        float4v bv = *(const float4v*)&Bg[o][tx * 4];
#pragma unroll
        for (int a = 0; a < 4; ++a)
#pragma unroll
            for (int b = 0; b < 4; ++b) acc[a][b] += av[a] * bv[b];
    }
#pragma unroll
    for (int a = 0; a < 4; ++a)
#pragma unroll
        for (int b = 0; b < 4; ++b)
            M2[((size_t)(i0 + ty * 4 + a) * 512 + (j0 + tx * 4 + b)) * 8 + g] = acc[a][b];
}

// ---------------- S-GEMM (trunc-split bf16, 3 passes) with fused att reduction ----------------
// S[b,i,j] = sum_d q[b,i,d]*k[b,j,d];  att_raw[b,g] += sum_{i,j in tile} M2[i,j,g]*S[b,i,j]
// hi = trunc16(x); res = x - hi (exact); lo = trunc16(res).  Dropped lo*lo term ~2^-14/product.
__global__ __launch_bounds__(256, 4) void sgemm_att_kernel(const float* __restrict__ q,
                                                           const float* __restrict__ kmat,
                                                           const float* __restrict__ M2,
                                                           float* __restrict__ att) {
    __shared__ __align__(16) short Ah[128 * 32];
    __shared__ __align__(16) short Al[128 * 32];
    __shared__ __align__(16) short Bh[128 * 32];
    __shared__ __align__(16) short Bl[128 * 32];
    __shared__ float wred[4][8];

    // XCD-chunked swizzle: each XCD gets 128 consecutive logical blocks = 8 batches
    int bid = blockIdx.x;
    int swz = (bid & 7) * 128 + (bid >> 3);
    int b  = swz >> 4;
    int t  = swz & 15;
    int i0 = (t & 3) * 128;
    int j0 = (t >> 2) * 128;
    const float* qb = q    + (size_t)b * CCH * DD;
    const float* kb = kmat + (size_t)b * CCH * DD;

    int tid  = threadIdx.x;
    int wave = tid >> 6, lane = tid & 63;
    int quad = lane >> 4, l15 = lane & 15;
    int wm = (wave >> 1) * 64, wn = (wave & 1) * 64;

    int srow = tid >> 3;               // staging row (0..31), +32 per r
    int sc4  = (tid & 7) * 4;          // staging col (shorts)
    const float* qp0 = qb + (size_t)(i0 + srow) * DD + sc4;
    const float* kp0 = kb + (size_t)(j0 + srow) * DD + sc4;

    float4v acc[4][4];
#pragma unroll
    for (int a = 0; a < 4; ++a)
#pragma unroll
        for (int c = 0; c < 4; ++c) acc[a][c] = (float4v){0.f, 0.f, 0.f, 0.f};

    for (int kt = 0; kt < DD; kt += 32) {
#pragma unroll
        for (int r = 0; r < 4; ++r) {
            int row = srow + r * 32;
            float4v qa = *(const float4v*)(qp0 + (size_t)r * 32 * DD + kt);
            float4v ka = *(const float4v*)(kp0 + (size_t)r * 32 * DD + kt);
            short4v qh, ql, kh, kl;
#pragma unroll
            for (int e = 0; e < 4; ++e) {
                union { float f; unsigned u; } cq; cq.f = qa[e];
                union { float f; unsigned u; } ck; ck.f = ka[e];
                qh[e] = (short)(cq.u >> 16);
                kh[e] = (short)(ck.u >> 16);
                union { unsigned u; float f; } hq; hq.u = cq.u & 0xffff0000u;
                union { unsigned u; float f; } hk; hk.u = ck.u & 0xffff0000u;
                union { float f; unsigned u; } rq; rq.f = qa[e] - hq.f;
                union { float f; unsigned u; } rk; rk.f = ka[e] - hk.f;
                ql[e] = (short)(rq.u >> 16);
                kl[e] = (short)(rk.u >> 16);
            }
            int wi = SWZI(row, sc4);
            *(short4v*)&Ah[wi] = qh;
            *(short4v*)&Al[wi] = ql;
            *(short4v*)&Bh[wi] = kh;
            *(short4v*)&Bl[wi] = kl;
        }
        __syncthreads();

        short8 ah[4], al[4];
#pragma unroll
        for (int mi = 0; mi < 4; ++mi) {
            int ri = SWZI(wm + mi * 16 + l15, quad * 8);
            ah[mi] = *(const short8*)&Ah[ri];
            al[mi] = *(const short8*)&Al[ri];
        }
#pragma unroll
        for (int ni = 0; ni < 4; ++ni) {
            int ri = SWZI(wn + ni * 16 + l15, quad * 8);
            short8 bh8 = *(const short8*)&Bh[ri];
            short8 bl8 = *(const short8*)&Bl[ri];
#pragma unroll
            for (int mi = 0; mi < 4; ++mi) {
                acc[mi][ni] = __builtin_amdgcn_mfma_f32_16x16x32_bf16(ah[mi], bh8, acc[mi][ni], 0, 0, 0);
                acc[mi][ni] = __builtin_amdgcn_mfma_f32_16x16x32_bf16(al[mi], bh8, acc[mi][ni], 0, 0, 0);
                acc[mi][ni] = __builtin_amdgcn_mfma_f32_16x16x32_bf16(ah[mi], bl8, acc[mi][ni], 0, 0, 0);
            }
        }
        __syncthreads();
    }

    // epilogue: att partials via M2 (layout [i][j][g], g contiguous)
    float r8[8] = {};
#pragma unroll
    for (int mi = 0; mi < 4; ++mi)
#pragma unroll
        for (int ni = 0; ni < 4; ++ni)
#pragma unroll
            for (int r = 0; r < 4; ++r) {
                int i = i0 + wm + mi * 16 + quad * 4 + r;
                int j = j0 + wn + ni * 16 + l15;
                float s = acc[mi][ni][r];
                const float* mp = M2 + ((size_t)i * 512 + j) * 8;
                float4v m0 = *(const float4v*)mp;
                float4v m1 = *(const float4v*)(mp + 4);
                r8[0] += s * m0[0]; r8[1] += s * m0[1]; r8[2] += s * m0[2]; r8[3] += s * m0[3];
                r8[4] += s * m1[0]; r8[5] += s * m1[1]; r8[6] += s * m1[2]; r8[7] += s * m1[3];
            }
#pragma unroll
    for (int off = 32; off > 0; off >>= 1)
#pragma unroll
        for (int g8 = 0; g8 < 8; ++g8)
            r8[g8] += __shfl_down(r8[g8], off, 64);
    if (lane == 0)
#pragma unroll
        for (int g8 = 0; g8 < 8; ++g8) wred[wave][g8] = r8[g8];
    __syncthreads();
    if (tid < 8)
        atomicAdd(&att[b * 8 + tid], wred[0][tid] + wred[1][tid] + wred[2][tid] + wred[3][tid]);
}

// ---------------- y-GEMM: y[b,o,d] = sum_c W2[o,c] * v[b,c,d]  (fp32 out into d_out)
// 512 threads / 8 waves; block = 256 o x 128 d => v read 2x.
// Fused per-wave GroupNorm partial stats (each wave's 64 o-rows = one (b,g) group).
__global__ __launch_bounds__(512, 4) void ygemm_kernel(const unsigned short* __restrict__ W2bf,
                                                       const float* __restrict__ v,
                                                       float* __restrict__ y,
                                                       float* __restrict__ ysum,
                                                       float* __restrict__ ysum2) {
    __shared__ __align__(16) short As[256 * 32];  // W2 tile: 256 o x 32 c (swizzled)
    __shared__ __align__(16) short Bs[128 * 32];  // v tile (transposed): 128 d x 32 c (swizzled)

    int bid = blockIdx.x;
    int swz = (bid & 7) * 128 + (bid >> 3);
    int b  = swz >> 4;
    int t  = swz & 15;
    int o0 = (t & 1) * 256;
    int d0 = (t >> 1) * 128;
    const float* vb = v + (size_t)b * CCH * DD;

    int tid  = threadIdx.x;
    int wave = tid >> 6, lane = tid & 63;
    int quad = lane >> 4, l15 = lane & 15;
    int wo = wave >> 1, wd = wave & 1;          // wave tile: 64 o x 64 d

    float4v acc[4][4];
#pragma unroll
    for (int a = 0; a < 4; ++a)
#pragma unroll
        for (int c = 0; c < 4; ++c) acc[a][c] = (float4v){0.f, 0.f, 0.f, 0.f};

    int nB = tid & 127;        // d-index within tile for B staging
    int kB = (tid >> 7) * 8;   // k octet base (0..24)

    for (int kt = 0; kt < CCH; kt += 32) {
        // A: W2 rows (already bf16, k-contiguous): 256x32 shorts = 1024 short8 / 512 thr
#pragma unroll
        for (int r = 0; r < 2; ++r) {
            int f   = tid + r * 512;
            int row = f >> 2;
            int c8  = (f & 3) * 8;
            short8 w = *(const short8*)(W2bf + (size_t)(o0 + row) * 512 + kt + c8);
            *(short8*)&As[SWZI(row, c8)] = w;
        }
        // B: transpose-gather v[c,d] -> Bs[d][c]: 128x32 = 512 short8 / 512 thr
        {
            short8 bsv;
#pragma unroll
            for (int jj = 0; jj < 8; ++jj) {
                float f = vb[(size_t)(kt + kB + jj) * DD + d0 + nB];
                bsv[jj] = f2bf(f);
            }
            *(short8*)&Bs[SWZI(nB, kB)] = bsv;
        }
        __syncthreads();

        short8 af[4], bf[4];
#pragma unroll
        for (int mi = 0; mi < 4; ++mi)
            af[mi] = *(const short8*)&As[SWZI(wo * 64 + mi * 16 + l15, quad * 8)];
#pragma unroll
        for (int ni = 0; ni < 4; ++ni)
            bf[ni] = *(const short8*)&Bs[SWZI(wd * 64 + ni * 16 + l15, quad * 8)];
#pragma unroll
        for (int mi = 0; mi < 4; ++mi)
#pragma unroll
            for (int ni = 0; ni < 4; ++ni)
                acc[mi][ni] = __builtin_amdgcn_mfma_f32_16x16x32_bf16(af[mi], bf[ni], acc[mi][ni], 0, 0, 0);
        __syncthreads();
    }

    float* yb = y + (size_t)b * CCH * DD;
    float s = 0.f, s2 = 0.f;
#pragma unroll
    for (int mi = 0; mi < 4; ++mi)
#pragma unroll
        for (int ni = 0; ni < 4; ++ni) {
            int o = o0 + wo * 64 + mi * 16 + quad * 4;
            int d = d0 + wd * 64 + ni * 16 + l15;
#pragma unroll
            for (int r = 0; r < 4; ++r) {
                float val = acc[mi][ni][r];
                yb[(size_t)(o + r) * DD + d] = val;
                s  += val;
                s2 += val * val;
            }
        }
    // wave-level reduce: all 64 o-rows of this wave are one (b,g) group
#pragma unroll
    for (int off = 32; off > 0; off >>= 1) {
        s  += __shfl_down(s, off, 64);
        s2 += __shfl_down(s2, off, 64);
    }
    if (lane == 0) {
        int g = (o0 >> 6) + wo;
        atomicAdd(&ysum[b * 8 + g], s);
        atomicAdd(&ysum2[b * 8 + g], s2);
    }
}

// ---------------- finalize: scl = a/sqrt(a^2*var+eps), mean  (from fused sums) ----------------
__global__ void finalize_kernel(const float* __restrict__ att,
                                const float* __restrict__ ysum,
                                const float* __restrict__ ysum2,
                                float* __restrict__ scl,
                                float* __restrict__ meanp) {
    int bg = threadIdx.x;
    if (bg < 512) {
        float inv = 1.0f / 65536.0f;
        float m = ysum[bg] * inv;
        float var = ysum2[bg] * inv - m * m;
        float a = att[bg] * SCALE_;
        scl[bg] = a / sqrtf(a * a * var + EPS_);
        meanp[bg] = m;
    }
}

// ---------------- final: out = gamma[c]*scl*(y-mean) + beta[c] + v  (in-place on d_out) ----------------
__global__ __launch_bounds__(256) void final_kernel(const float* __restrict__ v,
                                                    const float* __restrict__ gamma,
                                                    const float* __restrict__ beta,
                                                    const float* __restrict__ scl,
                                                    const float* __restrict__ meanp,
                                                    float* __restrict__ out) {
    size_t idx = ((size_t)blockIdx.x * 256 + threadIdx.x) * 4;
    int c  = (int)((idx >> 10) & 511);
    int bg = (int)(idx >> 19) * 8 + (c >> 6);
    float4v y4 = *(const float4v*)(out + idx);
    float4v v4 = *(const float4v*)(v + idx);
    float sc = scl[bg] * gamma[c];
    float sh = beta[c] - sc * meanp[bg];
    float4v o4;
    o4[0] = y4[0] * sc + sh + v4[0];
    o4[1] = y4[1] * sc + sh + v4[1];
    o4[2] = y4[2] * sc + sh + v4[2];
    o4[3] = y4[3] * sc + sh + v4[3];
    *(float4v*)(out + idx) = o4;
}

extern "C" void kernel_launch(void* const* d_in, const int* in_sizes, int n_in,
                              void* d_out, int out_size, void* d_ws, size_t ws_size,
                              hipStream_t stream) {
    const float* q     = (const float*)d_in[0];
    const float* kmat  = (const float*)d_in[1];
    const float* v     = (const float*)d_in[2];
    const float* Wt    = (const float*)d_in[3];
    const float* Wp    = (const float*)d_in[4];
    const float* Wg    = (const float*)d_in[5];
    const float* Wz    = (const float*)d_in[6];
    const float* gamma = (const float*)d_in[7];
    const float* beta  = (const float*)d_in[8];
    float* out = (float*)d_out;

    char* ws = (char*)d_ws;
    float*          M2    = (float*)ws;                       // 8 MB  (512*512*8 fp32)
    unsigned short* W2bf  = (unsigned short*)(ws + 8388608);  // 512 KB
    float*          att   = (float*)(ws + 8912896);           // 2 KB
    float*          ysum  = (float*)(ws + 8914944);           // 2 KB
    float*          ysum2 = (float*)(ws + 8916992);           // 2 KB
    float*          scl   = (float*)(ws + 8919040);           // 2 KB
    float*          meanp = (float*)(ws + 8921088);           // 2 KB

    hipLaunchKernelGGL(zero_att_kernel, dim3(1), dim3(512), 0, stream, att);
    hipLaunchKernelGGL(w2_kernel, dim3(1024), dim3(256), 0, stream, Wt, Wz, W2bf);
    hipLaunchKernelGGL(m2_kernel, dim3(512), dim3(256), 0, stream, Wp, Wg, M2);
    hipLaunchKernelGGL(sgemm_att_kernel, dim3(1024), dim3(256), 0, stream, q, kmat, M2, att);
    hipLaunchKernelGGL(ygemm_kernel, dim3(1024), dim3(512), 0, stream, W2bf, v, out, ysum, ysum2);
    hipLaunchKernelGGL(finalize_kernel, dim3(1), dim3(512), 0, stream, att, ysum, ysum2, scl, meanp);
    hipLaunchKernelGGL(final_kernel, dim3(32768), dim3(256), 0, stream, v, gamma, beta, scl, meanp, out);
}